// Round 7
// baseline (103.767 us; speedup 1.0000x reference)
//
#include <hip/hip_runtime.h>

#define BSZ 512
#define DIM 768
#define KSPLIT 4
#define KSEG (DIM / KSPLIT)   // 192
#define KT 32
#define NCHK (KSEG / KT)      // 6
#define TILE 64
#define NTYPES 16
#define MARGIN 1.0f
#define NBLK 256

// ---------------------------------------------------------------------------
// Single fused kernel, 256 blocks x 256 threads = 1 block/CU (co-resident ->
// grid barrier deadlock-free).  Saves 2 kernel-boundary L2 flush+launch
// costs (~6us each) vs the R6 3-launch structure.
//
// Phase 1: R6's K-split partial dot GEMM (4 ksplits x 64 tiles; 64x64 tile,
//   4x4 micro-tile: 2 ds_read_b128 feed 16 FMAs; double-buffered LDS).
//   Diagonal of summed dot = squared norms (no separate norms pass).
// Barrier: arrive with ONE agent-scope RELEASE add per block (after
//   __syncthreads drained all waves' stores to L2 -> single buffer_wbl2),
//   spin on RELAXED atomic loads (coherence-point polling, NO cache
//   invalidates -- R5's 87us disaster was ACQUIRE-per-poll = buffer_inv
//   storm), one ACQUIRE load at exit.
// Phase 2: 2 anchors/block: distance formed on the fly from 4 partials +
//   norms, ballot-compaction, |P|x|N| pair scan.
// Phase 3: ticket-elected last block computes exact integer V and writes
//   the scalar loss (invalid triplets contribute exactly margin, since the
//   reference adds margin to ALL entries before clamping).
// ---------------------------------------------------------------------------
__global__ __launch_bounds__(256) void fused_kernel(
    const float* __restrict__ emb, const int* __restrict__ types,
    float* __restrict__ part,       // [KSPLIT][BSZ][BSZ]
    float* __restrict__ ndiag,      // [KSPLIT][BSZ]
    double* __restrict__ accum,
    unsigned* __restrict__ ctrl,    // ctrl[0]=arrive, ctrl[1]=ticket
    float* __restrict__ out)
{
    const int tid = threadIdx.x;
    const int tx = tid & 15, ty = tid >> 4;
    const int blk = blockIdx.x;
    const int ks = blk >> 6;          // 0..3
    const int tile = blk & 63;        // 0..63
    const int ti = tile >> 3, tj = tile & 7;
    const int i0 = ti * TILE, j0 = tj * TILE;

    __shared__ float sA[2][KT][TILE + 4];
    __shared__ float sB[2][KT][TILE + 4];
    __shared__ float nrm[BSZ];
    __shared__ float pos[BSZ], neg[BSZ];
    __shared__ int npos, nneg;
    __shared__ float wsum[4];
    __shared__ int winner;
    __shared__ int cnt[NTYPES];

    // ---------------- phase 1: K-split partial dot tile ----------------
    {
        const int srow = tid >> 2;    // 0..63
        const int g = tid & 3;        // 0..3 -> float4 groups g, g+4
        const float* gA = emb + (size_t)(i0 + srow) * DIM + ks * KSEG;
        const float* gB = emb + (size_t)(j0 + srow) * DIM + ks * KSEG;

        float4 a0 = *(const float4*)(gA + 4 * g);
        float4 a1 = *(const float4*)(gA + 4 * (g + 4));
        float4 b0 = *(const float4*)(gB + 4 * g);
        float4 b1 = *(const float4*)(gB + 4 * (g + 4));
        {
            float (*pA)[TILE + 4] = sA[0];
            float (*pB)[TILE + 4] = sB[0];
            pA[4*g+0][srow]=a0.x; pA[4*g+1][srow]=a0.y; pA[4*g+2][srow]=a0.z; pA[4*g+3][srow]=a0.w;
            pA[4*(g+4)+0][srow]=a1.x; pA[4*(g+4)+1][srow]=a1.y; pA[4*(g+4)+2][srow]=a1.z; pA[4*(g+4)+3][srow]=a1.w;
            pB[4*g+0][srow]=b0.x; pB[4*g+1][srow]=b0.y; pB[4*g+2][srow]=b0.z; pB[4*g+3][srow]=b0.w;
            pB[4*(g+4)+0][srow]=b1.x; pB[4*(g+4)+1][srow]=b1.y; pB[4*(g+4)+2][srow]=b1.z; pB[4*(g+4)+3][srow]=b1.w;
        }
        __syncthreads();

        float acc[4][4] = {};
        for (int c = 0; c < NCHK; ++c) {
            const int cur = c & 1;
            float4 qa0, qa1, qb0, qb1;
            if (c + 1 < NCHK) {
                const float* pa = gA + (c + 1) * KT;
                const float* pb = gB + (c + 1) * KT;
                qa0 = *(const float4*)(pa + 4 * g);
                qa1 = *(const float4*)(pa + 4 * (g + 4));
                qb0 = *(const float4*)(pb + 4 * g);
                qb1 = *(const float4*)(pb + 4 * (g + 4));
            }
            #pragma unroll
            for (int k = 0; k < KT; ++k) {
                float4 av = *(const float4*)&sA[cur][k][4 * ty];
                float4 bv = *(const float4*)&sB[cur][k][4 * tx];
                acc[0][0] = fmaf(av.x, bv.x, acc[0][0]);
                acc[0][1] = fmaf(av.x, bv.y, acc[0][1]);
                acc[0][2] = fmaf(av.x, bv.z, acc[0][2]);
                acc[0][3] = fmaf(av.x, bv.w, acc[0][3]);
                acc[1][0] = fmaf(av.y, bv.x, acc[1][0]);
                acc[1][1] = fmaf(av.y, bv.y, acc[1][1]);
                acc[1][2] = fmaf(av.y, bv.z, acc[1][2]);
                acc[1][3] = fmaf(av.y, bv.w, acc[1][3]);
                acc[2][0] = fmaf(av.z, bv.x, acc[2][0]);
                acc[2][1] = fmaf(av.z, bv.y, acc[2][1]);
                acc[2][2] = fmaf(av.z, bv.z, acc[2][2]);
                acc[2][3] = fmaf(av.z, bv.w, acc[2][3]);
                acc[3][0] = fmaf(av.w, bv.x, acc[3][0]);
                acc[3][1] = fmaf(av.w, bv.y, acc[3][1]);
                acc[3][2] = fmaf(av.w, bv.z, acc[3][2]);
                acc[3][3] = fmaf(av.w, bv.w, acc[3][3]);
            }
            if (c + 1 < NCHK) {
                float (*pA)[TILE + 4] = sA[1 - cur];
                float (*pB)[TILE + 4] = sB[1 - cur];
                pA[4*g+0][srow]=qa0.x; pA[4*g+1][srow]=qa0.y; pA[4*g+2][srow]=qa0.z; pA[4*g+3][srow]=qa0.w;
                pA[4*(g+4)+0][srow]=qa1.x; pA[4*(g+4)+1][srow]=qa1.y; pA[4*(g+4)+2][srow]=qa1.z; pA[4*(g+4)+3][srow]=qa1.w;
                pB[4*g+0][srow]=qb0.x; pB[4*g+1][srow]=qb0.y; pB[4*g+2][srow]=qb0.z; pB[4*g+3][srow]=qb0.w;
                pB[4*(g+4)+0][srow]=qb1.x; pB[4*(g+4)+1][srow]=qb1.y; pB[4*(g+4)+2][srow]=qb1.z; pB[4*(g+4)+3][srow]=qb1.w;
            }
            __syncthreads();
        }

        float* pbuf = part + (size_t)ks * BSZ * BSZ;
        #pragma unroll
        for (int r = 0; r < 4; ++r) {
            const int gi = i0 + 4 * ty + r;
            float4 v = make_float4(acc[r][0], acc[r][1], acc[r][2], acc[r][3]);
            *(float4*)&pbuf[(size_t)gi * BSZ + j0 + 4 * tx] = v;
        }
        if (ti == tj && tx == ty) {
            #pragma unroll
            for (int r = 0; r < 4; ++r)
                ndiag[ks * BSZ + i0 + 4 * ty + r] = acc[r][r];
        }
    }

    // ---------------- grid barrier: release-arrive, RELAXED spin ----------
    __syncthreads();   // drains every wave's stores to L2 (vmcnt(0))
    if (tid == 0) {
        __hip_atomic_fetch_add(&ctrl[0], 1u, __ATOMIC_RELEASE,
                               __HIP_MEMORY_SCOPE_AGENT);   // one wbl2/block
        while (__hip_atomic_load(&ctrl[0], __ATOMIC_RELAXED,
                                 __HIP_MEMORY_SCOPE_AGENT) < NBLK)
            __builtin_amdgcn_s_sleep(2);                    // no cache ops
        (void)__hip_atomic_load(&ctrl[0], __ATOMIC_ACQUIRE,
                                __HIP_MEMORY_SCOPE_AGENT);  // single inv
    }
    __syncthreads();

    // ---------------- phase 2: 2 anchors per block -------------------------
    const int lane = tid & 63;
    for (int j = tid; j < BSZ; j += 256)
        nrm[j] = ndiag[j] + ndiag[BSZ + j] + ndiag[2 * BSZ + j] + ndiag[3 * BSZ + j];
    __syncthreads();

    const size_t PS = (size_t)BSZ * BSZ;
    double blocksum = 0.0;
    for (int ai = 0; ai < 2; ++ai) {
        const int a = blk * 2 + ai;
        if (tid == 0) { npos = 0; nneg = 0; }
        const int ta = types[a];
        const float na = nrm[a];
        const size_t rb = (size_t)a * BSZ;
        __syncthreads();

        for (int j = tid; j < BSZ; j += 256) {
            const float sp = part[rb + j] + part[PS + rb + j]
                           + part[2 * PS + rb + j] + part[3 * PS + rb + j];
            const float d = sqrtf(fmaxf(na + nrm[j] - 2.f * sp, 0.f));
            const bool isp = (types[j] == ta);
            const unsigned long long m = __ballot(isp);
            const unsigned long long below = m & ((1ull << lane) - 1ull);
            const int cp = __popcll(m);
            int basep = 0, basen = 0;
            if (lane == 0) {
                basep = atomicAdd(&npos, cp);
                basen = atomicAdd(&nneg, 64 - cp);
            }
            basep = __shfl(basep, 0);
            basen = __shfl(basen, 0);
            const int pbelow = (int)__popcll(below);
            if (isp) pos[basep + pbelow] = d;
            else     neg[basen + (lane - pbelow)] = d;
        }
        __syncthreads();
        const int np = npos, nn = nneg;

        float local = 0.f;
        for (int pi = 0; pi < np; ++pi) {
            const float dpm = pos[pi] + MARGIN;      // broadcast LDS read
            for (int n = tid; n < nn; n += 256)
                local += fmaxf(dpm - neg[n], 0.f);
        }

        #pragma unroll
        for (int off = 32; off > 0; off >>= 1) local += __shfl_down(local, off);
        if (lane == 0) wsum[tid >> 6] = local;
        __syncthreads();
        if (tid == 0)
            blocksum += (double)wsum[0] + (double)wsum[1]
                      + (double)wsum[2] + (double)wsum[3];
        __syncthreads();   // protect npos/nneg/wsum reuse next iteration
    }
    if (tid == 0) atomicAdd(accum, blocksum);

    // ---------------- phase 3: ticket-elected finalize ----------------------
    if (tid == 0) {
        unsigned t = __hip_atomic_fetch_add(&ctrl[1], 1u, __ATOMIC_ACQ_REL,
                                            __HIP_MEMORY_SCOPE_AGENT);
        winner = (t == NBLK - 1) ? 1 : 0;
    }
    __syncthreads();
    if (winner) {                        // block-uniform branch
        if (tid < NTYPES) cnt[tid] = 0;
        __syncthreads();
        for (int i = tid; i < BSZ; i += 256) atomicAdd(&cnt[types[i]], 1);
        __syncthreads();
        if (tid == 0) {
            long long V = 0;
            for (int t2 = 0; t2 < NTYPES; t2++) {
                long long c = cnt[t2];
                V += c * c * (long long)(BSZ - c);
            }
            const long long B3 = (long long)BSZ * BSZ * BSZ;
            double total = __hip_atomic_load(accum, __ATOMIC_ACQUIRE,
                                             __HIP_MEMORY_SCOPE_AGENT)
                         + (double)(B3 - V) * (double)MARGIN;
            out[0] = (float)(total / (double)V);
        }
    }
}

extern "C" void kernel_launch(void* const* d_in, const int* in_sizes, int n_in,
                              void* d_out, int out_size, void* d_ws, size_t ws_size,
                              hipStream_t stream) {
    const int* types = (const int*)d_in[0];
    const float* emb = (const float*)d_in[1];
    float* out = (float*)d_out;

    float* part = (float*)d_ws;                               // 4 MB
    float* ndiag = part + (size_t)KSPLIT * BSZ * BSZ;         // 8 KB
    char* tail = (char*)(ndiag + KSPLIT * BSZ);
    double* accum = (double*)tail;                            // 8 B
    unsigned* ctrl = (unsigned*)(tail + 8);                   // 8 B

    hipMemsetAsync(tail, 0, 16, stream);   // zero accum + ctrl (capturable)
    fused_kernel<<<NBLK, 256, 0, stream>>>(emb, types, part, ndiag,
                                           accum, ctrl, out);
}

// Round 8
// 93.058 us; speedup vs baseline: 1.1151x; 1.1151x over previous
//
#include <hip/hip_runtime.h>

#define BSZ 512
#define DIM 768
#define KSPLIT 16
#define KSEG (DIM / KSPLIT)   // 48
#define KT 16
#define NCHK (KSEG / KT)      // 3
#define TILE 128
#define PAD 4
#define NTYPES 16
#define MARGIN 1.0f
#define NBLK2 512             // triplet grid

// ---------------------------------------------------------------------------
// Kernel 1: K-split partial dot GEMM.  grid = 256 = 16 ksplits x 16 tiles
// (1 block/CU).  128x128 tile, KSEG=48 per block, 16x16 threads, 8x8
// micro-tile arranged as 2x2 quadrants of 4x4 (all LDS reads are float4 at
// stride 16B across tx -> <=2-way bank aliasing = free; av reads are 4-addr
// broadcasts).  1 B LDS-read per FMA (half of the R6 4x4 kernel, which was
// LDS-pipe-bound).  Double-buffered KT=16 chunks, register prefetch.
// Diagonal of the summed dot = squared norms -> ndiag partials.
// Block 0 zeroes accum+ctrl (visible to kernel 2 across the boundary --
// proven in R6).  NO grid sync: R5/R7 showed any in-kernel barrier loses
// ~35us to cache-maintenance storms; kernel boundaries are cheaper.
// ---------------------------------------------------------------------------
__global__ __launch_bounds__(256) void gemm_kernel(
    const float* __restrict__ emb,
    float* __restrict__ part,       // [KSPLIT][BSZ][BSZ]
    float* __restrict__ ndiag,      // [KSPLIT][BSZ]
    double* __restrict__ accum,
    unsigned* __restrict__ ctrl)
{
    const int tid = threadIdx.x;
    const int tx = tid & 15, ty = tid >> 4;
    const int blk = blockIdx.x;
    const int ks = blk >> 4;          // 0..15
    const int tile = blk & 15;        // 0..15
    const int ti = tile >> 2, tj = tile & 3;
    const int i0 = ti * TILE, j0 = tj * TILE;

    if (blk == 0 && tid == 0) { *accum = 0.0; ctrl[0] = 0u; }

    __shared__ __align__(16) float sA[2][KT][TILE + PAD];
    __shared__ __align__(16) float sB[2][KT][TILE + PAD];

    // staging: srow = tid>>1 (0..127), g = tid&1 -> float4 groups g and g+2
    const int srow = tid >> 1;
    const int g = tid & 1;
    const float* gA = emb + (size_t)(i0 + srow) * DIM + ks * KSEG + 4 * g;
    const float* gB = emb + (size_t)(j0 + srow) * DIM + ks * KSEG + 4 * g;

    float4 a0 = *(const float4*)gA;
    float4 a1 = *(const float4*)(gA + 8);
    float4 b0 = *(const float4*)gB;
    float4 b1 = *(const float4*)(gB + 8);
    {
        float (*pA)[TILE + PAD] = sA[0];
        float (*pB)[TILE + PAD] = sB[0];
        pA[4*g+0][srow]=a0.x; pA[4*g+1][srow]=a0.y; pA[4*g+2][srow]=a0.z; pA[4*g+3][srow]=a0.w;
        pA[4*g+8][srow]=a1.x; pA[4*g+9][srow]=a1.y; pA[4*g+10][srow]=a1.z; pA[4*g+11][srow]=a1.w;
        pB[4*g+0][srow]=b0.x; pB[4*g+1][srow]=b0.y; pB[4*g+2][srow]=b0.z; pB[4*g+3][srow]=b0.w;
        pB[4*g+8][srow]=b1.x; pB[4*g+9][srow]=b1.y; pB[4*g+10][srow]=b1.z; pB[4*g+11][srow]=b1.w;
    }
    __syncthreads();

    float acc[2][2][4][4] = {};

#define FMA4(AR, AV, BV) \
    AR[0] = fmaf(AV, BV.x, AR[0]); AR[1] = fmaf(AV, BV.y, AR[1]); \
    AR[2] = fmaf(AV, BV.z, AR[2]); AR[3] = fmaf(AV, BV.w, AR[3]);

    for (int c = 0; c < NCHK; ++c) {
        const int cur = c & 1;
        float4 qa0, qa1, qb0, qb1;
        if (c + 1 < NCHK) {
            qa0 = *(const float4*)(gA + (c + 1) * KT);
            qa1 = *(const float4*)(gA + (c + 1) * KT + 8);
            qb0 = *(const float4*)(gB + (c + 1) * KT);
            qb1 = *(const float4*)(gB + (c + 1) * KT + 8);
        }
        #pragma unroll
        for (int k = 0; k < KT; ++k) {
            float4 av0 = *(const float4*)&sA[cur][k][4 * ty];
            float4 av1 = *(const float4*)&sA[cur][k][64 + 4 * ty];
            float4 bv0 = *(const float4*)&sB[cur][k][4 * tx];
            float4 bv1 = *(const float4*)&sB[cur][k][64 + 4 * tx];
            FMA4(acc[0][0][0], av0.x, bv0); FMA4(acc[0][1][0], av0.x, bv1);
            FMA4(acc[0][0][1], av0.y, bv0); FMA4(acc[0][1][1], av0.y, bv1);
            FMA4(acc[0][0][2], av0.z, bv0); FMA4(acc[0][1][2], av0.z, bv1);
            FMA4(acc[0][0][3], av0.w, bv0); FMA4(acc[0][1][3], av0.w, bv1);
            FMA4(acc[1][0][0], av1.x, bv0); FMA4(acc[1][1][0], av1.x, bv1);
            FMA4(acc[1][0][1], av1.y, bv0); FMA4(acc[1][1][1], av1.y, bv1);
            FMA4(acc[1][0][2], av1.z, bv0); FMA4(acc[1][1][2], av1.z, bv1);
            FMA4(acc[1][0][3], av1.w, bv0); FMA4(acc[1][1][3], av1.w, bv1);
        }
        if (c + 1 < NCHK) {
            float (*pA)[TILE + PAD] = sA[1 - cur];
            float (*pB)[TILE + PAD] = sB[1 - cur];
            pA[4*g+0][srow]=qa0.x; pA[4*g+1][srow]=qa0.y; pA[4*g+2][srow]=qa0.z; pA[4*g+3][srow]=qa0.w;
            pA[4*g+8][srow]=qa1.x; pA[4*g+9][srow]=qa1.y; pA[4*g+10][srow]=qa1.z; pA[4*g+11][srow]=qa1.w;
            pB[4*g+0][srow]=qb0.x; pB[4*g+1][srow]=qb0.y; pB[4*g+2][srow]=qb0.z; pB[4*g+3][srow]=qb0.w;
            pB[4*g+8][srow]=qb1.x; pB[4*g+9][srow]=qb1.y; pB[4*g+10][srow]=qb1.z; pB[4*g+11][srow]=qb1.w;
        }
        __syncthreads();
    }
#undef FMA4

    // epilogue: 2x2 quadrants, coalesced float4 stores
    float* pbuf = part + (size_t)ks * BSZ * BSZ;
    #pragma unroll
    for (int ai = 0; ai < 2; ++ai) {
        #pragma unroll
        for (int r = 0; r < 4; ++r) {
            const int row = i0 + ai * 64 + 4 * ty + r;
            float* prow = pbuf + (size_t)row * BSZ;
            *(float4*)&prow[j0 + 4 * tx] =
                make_float4(acc[ai][0][r][0], acc[ai][0][r][1], acc[ai][0][r][2], acc[ai][0][r][3]);
            *(float4*)&prow[j0 + 64 + 4 * tx] =
                make_float4(acc[ai][1][r][0], acc[ai][1][r][1], acc[ai][1][r][2], acc[ai][1][r][3]);
        }
    }
    // diagonal tiles: partial diagonal = partial squared norms
    if (ti == tj && tx == ty) {
        #pragma unroll
        for (int ai = 0; ai < 2; ++ai)
            #pragma unroll
            for (int r = 0; r < 4; ++r)
                ndiag[ks * BSZ + i0 + ai * 64 + 4 * ty + r] = acc[ai][ai][r][r];
    }
}

// ---------------------------------------------------------------------------
// Kernel 2: per-anchor triplet sum + ticket-elected finalize (last block to
// finish computes exact integer V and writes the loss -- no co-residency
// needed, no extra kernel boundary).  Norms computed inline from ndiag
// (16 broadcast loads per j -- same load count as staging, one less
// barrier).  Distance formed on the fly from the 16 K-split partials.
// Ballot compaction -> |P| x |N| pair scan (same-type j's incl. j==a are
// positives; invalid triplets contribute exactly margin since the reference
// adds margin to ALL entries before clamping).
// ---------------------------------------------------------------------------
__global__ __launch_bounds__(256) void triplet_kernel(
    const float* __restrict__ part, const float* __restrict__ ndiag,
    const int* __restrict__ types, double* __restrict__ accum,
    unsigned* __restrict__ ctrl, float* __restrict__ out)
{
    const int a = blockIdx.x;
    const int tid = threadIdx.x;
    const int lane = tid & 63;
    __shared__ float pos[BSZ], neg[BSZ];
    __shared__ int npos, nneg;
    __shared__ float wsum[4];
    __shared__ int winner;
    __shared__ int cnt[NTYPES];
    if (tid == 0) { npos = 0; nneg = 0; }
    const int ta = types[a];

    float na = 0.f;
    #pragma unroll
    for (int s = 0; s < KSPLIT; ++s) na += ndiag[s * BSZ + a];   // broadcast
    __syncthreads();

    const size_t PS = (size_t)BSZ * BSZ;
    const size_t rb = (size_t)a * BSZ;

    for (int j = tid; j < BSZ; j += 256) {
        float sp = 0.f, nj = 0.f;
        #pragma unroll
        for (int s = 0; s < KSPLIT; ++s) {
            sp += part[s * PS + rb + j];
            nj += ndiag[s * BSZ + j];
        }
        const float d = sqrtf(fmaxf(na + nj - 2.f * sp, 0.f));
        const bool isp = (types[j] == ta);
        const unsigned long long m = __ballot(isp);
        const unsigned long long below = m & ((1ull << lane) - 1ull);
        const int cp = __popcll(m);
        int basep = 0, basen = 0;
        if (lane == 0) {
            basep = atomicAdd(&npos, cp);
            basen = atomicAdd(&nneg, 64 - cp);
        }
        basep = __shfl(basep, 0);
        basen = __shfl(basen, 0);
        const int pbelow = (int)__popcll(below);
        if (isp) pos[basep + pbelow] = d;
        else     neg[basen + (lane - pbelow)] = d;
    }
    __syncthreads();
    const int np = npos, nn = nneg;

    float local = 0.f;
    for (int pi = 0; pi < np; ++pi) {
        const float dpm = pos[pi] + MARGIN;          // broadcast LDS read
        for (int n = tid; n < nn; n += 256)
            local += fmaxf(dpm - neg[n], 0.f);
    }

    #pragma unroll
    for (int off = 32; off > 0; off >>= 1) local += __shfl_down(local, off);
    if (lane == 0) wsum[tid >> 6] = local;
    __syncthreads();
    if (tid == 0) {
        double s = (double)wsum[0] + (double)wsum[1] + (double)wsum[2] + (double)wsum[3];
        atomicAdd(accum, s);
        // ticket: RELEASE orders our accum add before the increment
        unsigned t = __hip_atomic_fetch_add(&ctrl[0], 1u, __ATOMIC_ACQ_REL,
                                            __HIP_MEMORY_SCOPE_AGENT);
        winner = (t == NBLK2 - 1) ? 1 : 0;
    }
    __syncthreads();
    if (winner) {                        // block-uniform branch, last finisher
        if (tid < NTYPES) cnt[tid] = 0;
        __syncthreads();
        for (int i = tid; i < BSZ; i += 256) atomicAdd(&cnt[types[i]], 1);
        __syncthreads();
        if (tid == 0) {
            long long V = 0;
            for (int t2 = 0; t2 < NTYPES; t2++) {
                long long c = cnt[t2];
                V += c * c * (long long)(BSZ - c);
            }
            const long long B3 = (long long)BSZ * BSZ * BSZ;
            double total = __hip_atomic_load(accum, __ATOMIC_ACQUIRE,
                                             __HIP_MEMORY_SCOPE_AGENT)
                         + (double)(B3 - V) * (double)MARGIN;
            out[0] = (float)(total / (double)V);
        }
    }
}

extern "C" void kernel_launch(void* const* d_in, const int* in_sizes, int n_in,
                              void* d_out, int out_size, void* d_ws, size_t ws_size,
                              hipStream_t stream) {
    const int* types = (const int*)d_in[0];
    const float* emb = (const float*)d_in[1];
    float* out = (float*)d_out;

    float* part = (float*)d_ws;                               // 16 MB
    float* ndiag = part + (size_t)KSPLIT * BSZ * BSZ;         // 32 KB
    char* tail = (char*)(ndiag + KSPLIT * BSZ);
    double* accum = (double*)tail;                            // 8 B
    unsigned* ctrl = (unsigned*)(tail + 8);                   // 4 B

    gemm_kernel<<<256, 256, 0, stream>>>(emb, part, ndiag, accum, ctrl);
    triplet_kernel<<<NBLK2, 256, 0, stream>>>(part, ndiag, types, accum, ctrl, out);
}

// Round 9
// 87.416 us; speedup vs baseline: 1.1871x; 1.0645x over previous
//
#include <hip/hip_runtime.h>

#define BSZ 512
#define DIM 768
#define KSPLIT 4
#define KSEG (DIM / KSPLIT)   // 192
#define KT 32
#define NCHK (KSEG / KT)      // 6
#define TILE 64
#define NTYPES 16
#define MARGIN 1.0f
#define NBLK2 512             // triplet grid

// ---------------------------------------------------------------------------
// Kernel 1: K-split partial dot GEMM — byte-identical to the proven R6
// kernel (80.3us total), except block 0 also zeroes ctrl[0] for kernel 2's
// ticket.  grid = 256 = 4 ksplits x 64 tiles (1 block/CU).  64x64 tile,
// 4x4 micro-tile (2 ds_read_b128 feed 16 FMAs), double-buffered LDS,
// k-major layout pad +4.  Diagonal of summed dot = squared norms -> ndiag.
// NO in-kernel grid sync ever: R5/R7 measured 35-50us penalties from
// agent-scope fence cache-maintenance; kernel boundaries are cheaper.
// KSPLIT=4 (4MB partials) beats KSPLIT=16 (R8: +13us from traffic + fill
// slowdown + 4x triplet VMEM).
// ---------------------------------------------------------------------------
__global__ __launch_bounds__(256) void dot_partial_kernel(
    const float* __restrict__ emb,
    float* __restrict__ part,       // [KSPLIT][BSZ][BSZ]
    float* __restrict__ ndiag,      // [KSPLIT][BSZ]
    double* __restrict__ accum,
    unsigned* __restrict__ ctrl)
{
    const int tid = threadIdx.x;
    const int tx = tid & 15, ty = tid >> 4;
    const int blk = blockIdx.x;
    const int ks = blk >> 6;          // 0..3
    const int tile = blk & 63;        // 0..63
    const int ti = tile >> 3, tj = tile & 7;
    const int i0 = ti * TILE, j0 = tj * TILE;

    if (blk == 0 && tid == 0) { *accum = 0.0; ctrl[0] = 0u; }

    __shared__ float sA[2][KT][TILE + 4];
    __shared__ float sB[2][KT][TILE + 4];

    const int srow = tid >> 2;
    const int g = tid & 3;
    const float* gA = emb + (size_t)(i0 + srow) * DIM + ks * KSEG;
    const float* gB = emb + (size_t)(j0 + srow) * DIM + ks * KSEG;

    float4 a0 = *(const float4*)(gA + 4 * g);
    float4 a1 = *(const float4*)(gA + 4 * (g + 4));
    float4 b0 = *(const float4*)(gB + 4 * g);
    float4 b1 = *(const float4*)(gB + 4 * (g + 4));

    {
        float (*pA)[TILE + 4] = sA[0];
        float (*pB)[TILE + 4] = sB[0];
        pA[4*g+0][srow]=a0.x; pA[4*g+1][srow]=a0.y; pA[4*g+2][srow]=a0.z; pA[4*g+3][srow]=a0.w;
        pA[4*(g+4)+0][srow]=a1.x; pA[4*(g+4)+1][srow]=a1.y; pA[4*(g+4)+2][srow]=a1.z; pA[4*(g+4)+3][srow]=a1.w;
        pB[4*g+0][srow]=b0.x; pB[4*g+1][srow]=b0.y; pB[4*g+2][srow]=b0.z; pB[4*g+3][srow]=b0.w;
        pB[4*(g+4)+0][srow]=b1.x; pB[4*(g+4)+1][srow]=b1.y; pB[4*(g+4)+2][srow]=b1.z; pB[4*(g+4)+3][srow]=b1.w;
    }
    __syncthreads();

    float acc[4][4] = {};

    for (int c = 0; c < NCHK; ++c) {
        const int cur = c & 1;
        float4 qa0, qa1, qb0, qb1;
        if (c + 1 < NCHK) {
            const float* pa = gA + (c + 1) * KT;
            const float* pb = gB + (c + 1) * KT;
            qa0 = *(const float4*)(pa + 4 * g);
            qa1 = *(const float4*)(pa + 4 * (g + 4));
            qb0 = *(const float4*)(pb + 4 * g);
            qb1 = *(const float4*)(pb + 4 * (g + 4));
        }
        #pragma unroll
        for (int k = 0; k < KT; ++k) {
            float4 av = *(const float4*)&sA[cur][k][4 * ty];
            float4 bv = *(const float4*)&sB[cur][k][4 * tx];
            acc[0][0] = fmaf(av.x, bv.x, acc[0][0]);
            acc[0][1] = fmaf(av.x, bv.y, acc[0][1]);
            acc[0][2] = fmaf(av.x, bv.z, acc[0][2]);
            acc[0][3] = fmaf(av.x, bv.w, acc[0][3]);
            acc[1][0] = fmaf(av.y, bv.x, acc[1][0]);
            acc[1][1] = fmaf(av.y, bv.y, acc[1][1]);
            acc[1][2] = fmaf(av.y, bv.z, acc[1][2]);
            acc[1][3] = fmaf(av.y, bv.w, acc[1][3]);
            acc[2][0] = fmaf(av.z, bv.x, acc[2][0]);
            acc[2][1] = fmaf(av.z, bv.y, acc[2][1]);
            acc[2][2] = fmaf(av.z, bv.z, acc[2][2]);
            acc[2][3] = fmaf(av.z, bv.w, acc[2][3]);
            acc[3][0] = fmaf(av.w, bv.x, acc[3][0]);
            acc[3][1] = fmaf(av.w, bv.y, acc[3][1]);
            acc[3][2] = fmaf(av.w, bv.z, acc[3][2]);
            acc[3][3] = fmaf(av.w, bv.w, acc[3][3]);
        }
        if (c + 1 < NCHK) {
            float (*pA)[TILE + 4] = sA[1 - cur];
            float (*pB)[TILE + 4] = sB[1 - cur];
            pA[4*g+0][srow]=qa0.x; pA[4*g+1][srow]=qa0.y; pA[4*g+2][srow]=qa0.z; pA[4*g+3][srow]=qa0.w;
            pA[4*(g+4)+0][srow]=qa1.x; pA[4*(g+4)+1][srow]=qa1.y; pA[4*(g+4)+2][srow]=qa1.z; pA[4*(g+4)+3][srow]=qa1.w;
            pB[4*g+0][srow]=qb0.x; pB[4*g+1][srow]=qb0.y; pB[4*g+2][srow]=qb0.z; pB[4*g+3][srow]=qb0.w;
            pB[4*(g+4)+0][srow]=qb1.x; pB[4*(g+4)+1][srow]=qb1.y; pB[4*(g+4)+2][srow]=qb1.z; pB[4*(g+4)+3][srow]=qb1.w;
        }
        __syncthreads();
    }

    float* pbuf = part + (size_t)ks * BSZ * BSZ;
    #pragma unroll
    for (int r = 0; r < 4; ++r) {
        const int gi = i0 + 4 * ty + r;
        float4 v = make_float4(acc[r][0], acc[r][1], acc[r][2], acc[r][3]);
        *(float4*)&pbuf[(size_t)gi * BSZ + j0 + 4 * tx] = v;
    }
    if (ti == tj && tx == ty) {
        #pragma unroll
        for (int r = 0; r < 4; ++r)
            ndiag[ks * BSZ + i0 + 4 * ty + r] = acc[r][r];
    }
}

// ---------------------------------------------------------------------------
// Kernel 2: per-anchor triplet sum (R6 form: nrm staged in LDS from 4
// ndiag partials, distance on the fly from 4 part streams, ballot
// compaction, |P|x|N| scan) + ticket-elected finalize (proven correct in
// R8): the last block to finish computes exact integer V and writes the
// loss — saves the third kernel launch.  Invalid triplets contribute
// exactly margin (reference adds margin to ALL entries pre-clamp).
// ---------------------------------------------------------------------------
__global__ __launch_bounds__(256) void triplet_kernel(
    const float* __restrict__ part, const float* __restrict__ ndiag,
    const int* __restrict__ types, double* __restrict__ accum,
    unsigned* __restrict__ ctrl, float* __restrict__ out)
{
    const int a = blockIdx.x;
    const int tid = threadIdx.x;
    const int lane = tid & 63;
    __shared__ float nrm[BSZ];
    __shared__ float pos[BSZ], neg[BSZ];
    __shared__ int npos, nneg;
    __shared__ float wsum[4];
    __shared__ int winner;
    __shared__ int cnt[NTYPES];
    if (tid == 0) { npos = 0; nneg = 0; }
    for (int j = tid; j < BSZ; j += 256)
        nrm[j] = ndiag[j] + ndiag[BSZ + j] + ndiag[2 * BSZ + j] + ndiag[3 * BSZ + j];
    const int ta = types[a];
    __syncthreads();

    const float na = nrm[a];
    const size_t rb = (size_t)a * BSZ;
    const size_t PS = (size_t)BSZ * BSZ;

    for (int j = tid; j < BSZ; j += 256) {
        const float sp = part[rb + j] + part[PS + rb + j]
                       + part[2 * PS + rb + j] + part[3 * PS + rb + j];
        const float d = sqrtf(fmaxf(na + nrm[j] - 2.f * sp, 0.f));
        const bool isp = (types[j] == ta);
        const unsigned long long m = __ballot(isp);
        const unsigned long long below = m & ((1ull << lane) - 1ull);
        const int cp = __popcll(m);
        int basep = 0, basen = 0;
        if (lane == 0) {
            basep = atomicAdd(&npos, cp);
            basen = atomicAdd(&nneg, 64 - cp);
        }
        basep = __shfl(basep, 0);
        basen = __shfl(basen, 0);
        const int pbelow = (int)__popcll(below);
        if (isp) pos[basep + pbelow] = d;
        else     neg[basen + (lane - pbelow)] = d;
    }
    __syncthreads();
    const int np = npos, nn = nneg;

    float local = 0.f;
    for (int pi = 0; pi < np; ++pi) {
        const float dpm = pos[pi] + MARGIN;          // broadcast LDS read
        for (int n = tid; n < nn; n += 256)
            local += fmaxf(dpm - neg[n], 0.f);
    }

    #pragma unroll
    for (int off = 32; off > 0; off >>= 1) local += __shfl_down(local, off);
    if (lane == 0) wsum[tid >> 6] = local;
    __syncthreads();
    if (tid == 0) {
        double s = (double)wsum[0] + (double)wsum[1] + (double)wsum[2] + (double)wsum[3];
        atomicAdd(accum, s);
        // ticket: ACQ_REL orders our accum add before the increment
        unsigned t = __hip_atomic_fetch_add(&ctrl[0], 1u, __ATOMIC_ACQ_REL,
                                            __HIP_MEMORY_SCOPE_AGENT);
        winner = (t == NBLK2 - 1) ? 1 : 0;
    }
    __syncthreads();
    if (winner) {                        // block-uniform branch, last finisher
        if (tid < NTYPES) cnt[tid] = 0;
        __syncthreads();
        for (int i = tid; i < BSZ; i += 256) atomicAdd(&cnt[types[i]], 1);
        __syncthreads();
        if (tid == 0) {
            long long V = 0;
            for (int t2 = 0; t2 < NTYPES; t2++) {
                long long c = cnt[t2];
                V += c * c * (long long)(BSZ - c);
            }
            const long long B3 = (long long)BSZ * BSZ * BSZ;
            double total = __hip_atomic_load(accum, __ATOMIC_ACQUIRE,
                                             __HIP_MEMORY_SCOPE_AGENT)
                         + (double)(B3 - V) * (double)MARGIN;
            out[0] = (float)(total / (double)V);
        }
    }
}

extern "C" void kernel_launch(void* const* d_in, const int* in_sizes, int n_in,
                              void* d_out, int out_size, void* d_ws, size_t ws_size,
                              hipStream_t stream) {
    const int* types = (const int*)d_in[0];
    const float* emb = (const float*)d_in[1];
    float* out = (float*)d_out;

    float* part = (float*)d_ws;                               // 4 MB
    float* ndiag = part + (size_t)KSPLIT * BSZ * BSZ;         // 8 KB
    char* tail = (char*)(ndiag + KSPLIT * BSZ);
    double* accum = (double*)tail;                            // 8 B
    unsigned* ctrl = (unsigned*)(tail + 8);                   // 4 B

    dot_partial_kernel<<<256, 256, 0, stream>>>(emb, part, ndiag, accum, ctrl);
    triplet_kernel<<<NBLK2, 256, 0, stream>>>(part, ndiag, types, accum, ctrl, out);
}

// Round 10
// 79.041 us; speedup vs baseline: 1.3128x; 1.1060x over previous
//
#include <hip/hip_runtime.h>

#define BSZ 512
#define DIM 768
#define KSPLIT 4
#define KSEG (DIM / KSPLIT)   // 192
#define KT 32
#define NCHK (KSEG / KT)      // 6
#define TILE 64
#define NTYPES 16
#define MARGIN 1.0f

// ---------------------------------------------------------------------------
// Kernel 1: K-split partial dot GEMM — identical to the proven R6 kernel
// (80.3us total), except block 0 zeroes out[0] (cross-boundary visibility
// proven in R6/R9).  grid = 256 = 4 ksplits x 64 tiles (1 block/CU).
// 64x64 tile, 4x4 micro-tile (2 ds_read_b128 feed 16 FMAs), double-buffered
// LDS, k-major layout pad +4.  Diagonal of summed dot = squared norms.
// NO grid sync / NO agent-scope acquire-release anywhere: R5/R7/R9 all
// measured 7-50us penalties from per-block cache-maintenance (buffer_inv
// storms); kernel boundaries + relaxed atomics only.
// ---------------------------------------------------------------------------
__global__ __launch_bounds__(256) void dot_partial_kernel(
    const float* __restrict__ emb,
    float* __restrict__ part,       // [KSPLIT][BSZ][BSZ]
    float* __restrict__ ndiag,      // [KSPLIT][BSZ]
    float* __restrict__ out)
{
    const int tid = threadIdx.x;
    const int tx = tid & 15, ty = tid >> 4;
    const int blk = blockIdx.x;
    const int ks = blk >> 6;          // 0..3
    const int tile = blk & 63;        // 0..63
    const int ti = tile >> 3, tj = tile & 7;
    const int i0 = ti * TILE, j0 = tj * TILE;

    if (blk == 0 && tid == 0) out[0] = 0.f;   // out is poisoned each launch

    __shared__ float sA[2][KT][TILE + 4];
    __shared__ float sB[2][KT][TILE + 4];

    const int srow = tid >> 2;
    const int g = tid & 3;
    const float* gA = emb + (size_t)(i0 + srow) * DIM + ks * KSEG;
    const float* gB = emb + (size_t)(j0 + srow) * DIM + ks * KSEG;

    float4 a0 = *(const float4*)(gA + 4 * g);
    float4 a1 = *(const float4*)(gA + 4 * (g + 4));
    float4 b0 = *(const float4*)(gB + 4 * g);
    float4 b1 = *(const float4*)(gB + 4 * (g + 4));

    {
        float (*pA)[TILE + 4] = sA[0];
        float (*pB)[TILE + 4] = sB[0];
        pA[4*g+0][srow]=a0.x; pA[4*g+1][srow]=a0.y; pA[4*g+2][srow]=a0.z; pA[4*g+3][srow]=a0.w;
        pA[4*(g+4)+0][srow]=a1.x; pA[4*(g+4)+1][srow]=a1.y; pA[4*(g+4)+2][srow]=a1.z; pA[4*(g+4)+3][srow]=a1.w;
        pB[4*g+0][srow]=b0.x; pB[4*g+1][srow]=b0.y; pB[4*g+2][srow]=b0.z; pB[4*g+3][srow]=b0.w;
        pB[4*(g+4)+0][srow]=b1.x; pB[4*(g+4)+1][srow]=b1.y; pB[4*(g+4)+2][srow]=b1.z; pB[4*(g+4)+3][srow]=b1.w;
    }
    __syncthreads();

    float acc[4][4] = {};

    for (int c = 0; c < NCHK; ++c) {
        const int cur = c & 1;
        float4 qa0, qa1, qb0, qb1;
        if (c + 1 < NCHK) {
            const float* pa = gA + (c + 1) * KT;
            const float* pb = gB + (c + 1) * KT;
            qa0 = *(const float4*)(pa + 4 * g);
            qa1 = *(const float4*)(pa + 4 * (g + 4));
            qb0 = *(const float4*)(pb + 4 * g);
            qb1 = *(const float4*)(pb + 4 * (g + 4));
        }
        #pragma unroll
        for (int k = 0; k < KT; ++k) {
            float4 av = *(const float4*)&sA[cur][k][4 * ty];
            float4 bv = *(const float4*)&sB[cur][k][4 * tx];
            acc[0][0] = fmaf(av.x, bv.x, acc[0][0]);
            acc[0][1] = fmaf(av.x, bv.y, acc[0][1]);
            acc[0][2] = fmaf(av.x, bv.z, acc[0][2]);
            acc[0][3] = fmaf(av.x, bv.w, acc[0][3]);
            acc[1][0] = fmaf(av.y, bv.x, acc[1][0]);
            acc[1][1] = fmaf(av.y, bv.y, acc[1][1]);
            acc[1][2] = fmaf(av.y, bv.z, acc[1][2]);
            acc[1][3] = fmaf(av.y, bv.w, acc[1][3]);
            acc[2][0] = fmaf(av.z, bv.x, acc[2][0]);
            acc[2][1] = fmaf(av.z, bv.y, acc[2][1]);
            acc[2][2] = fmaf(av.z, bv.z, acc[2][2]);
            acc[2][3] = fmaf(av.z, bv.w, acc[2][3]);
            acc[3][0] = fmaf(av.w, bv.x, acc[3][0]);
            acc[3][1] = fmaf(av.w, bv.y, acc[3][1]);
            acc[3][2] = fmaf(av.w, bv.z, acc[3][2]);
            acc[3][3] = fmaf(av.w, bv.w, acc[3][3]);
        }
        if (c + 1 < NCHK) {
            float (*pA)[TILE + 4] = sA[1 - cur];
            float (*pB)[TILE + 4] = sB[1 - cur];
            pA[4*g+0][srow]=qa0.x; pA[4*g+1][srow]=qa0.y; pA[4*g+2][srow]=qa0.z; pA[4*g+3][srow]=qa0.w;
            pA[4*(g+4)+0][srow]=qa1.x; pA[4*(g+4)+1][srow]=qa1.y; pA[4*(g+4)+2][srow]=qa1.z; pA[4*(g+4)+3][srow]=qa1.w;
            pB[4*g+0][srow]=qb0.x; pB[4*g+1][srow]=qb0.y; pB[4*g+2][srow]=qb0.z; pB[4*g+3][srow]=qb0.w;
            pB[4*(g+4)+0][srow]=qb1.x; pB[4*(g+4)+1][srow]=qb1.y; pB[4*(g+4)+2][srow]=qb1.z; pB[4*(g+4)+3][srow]=qb1.w;
        }
        __syncthreads();
    }

    float* pbuf = part + (size_t)ks * BSZ * BSZ;
    #pragma unroll
    for (int r = 0; r < 4; ++r) {
        const int gi = i0 + 4 * ty + r;
        float4 v = make_float4(acc[r][0], acc[r][1], acc[r][2], acc[r][3]);
        *(float4*)&pbuf[(size_t)gi * BSZ + j0 + 4 * tx] = v;
    }
    if (ti == tj && tx == ty) {
        #pragma unroll
        for (int r = 0; r < 4; ++r)
            ndiag[ks * BSZ + i0 + 4 * ty + r] = acc[r][r];
    }
}

// ---------------------------------------------------------------------------
// Kernel 2: per-anchor triplet sum, fully self-contained finalization.
// R6's proven pair-scan (nrm staged in LDS, distance on the fly from 4
// partial streams, ballot compaction, |P|x|N| scan).  Each block computes
// V REDUNDANTLY from a local LDS type-histogram (cheap, parallel) and
// atomically adds its own (blocksum / V) to out[0] — one plain device
// atomicAdd per block, NO acquire/release, NO ticket, NO extra kernel.
// Block 0 also adds the closed-form invalid-triplet term (B^3-V)*margin/V
// (each invalid triplet contributes exactly margin since the reference
// adds margin to ALL entries before clamping).
// ---------------------------------------------------------------------------
__global__ __launch_bounds__(256) void triplet_kernel(
    const float* __restrict__ part, const float* __restrict__ ndiag,
    const int* __restrict__ types, float* __restrict__ out)
{
    const int a = blockIdx.x;
    const int tid = threadIdx.x;
    const int lane = tid & 63;
    __shared__ float nrm[BSZ];
    __shared__ float pos[BSZ], neg[BSZ];
    __shared__ int npos, nneg;
    __shared__ float wsum[4];
    __shared__ int cnt[NTYPES];
    if (tid == 0) { npos = 0; nneg = 0; }
    if (tid < NTYPES) cnt[tid] = 0;
    for (int j = tid; j < BSZ; j += 256)
        nrm[j] = ndiag[j] + ndiag[BSZ + j] + ndiag[2 * BSZ + j] + ndiag[3 * BSZ + j];
    const int ta = types[a];
    __syncthreads();

    const float na = nrm[a];
    const size_t rb = (size_t)a * BSZ;
    const size_t PS = (size_t)BSZ * BSZ;

    for (int j = tid; j < BSZ; j += 256) {
        const int tj = types[j];
        atomicAdd(&cnt[tj], 1);                      // local histogram for V
        const float sp = part[rb + j] + part[PS + rb + j]
                       + part[2 * PS + rb + j] + part[3 * PS + rb + j];
        const float d = sqrtf(fmaxf(na + nrm[j] - 2.f * sp, 0.f));
        const bool isp = (tj == ta);
        const unsigned long long m = __ballot(isp);
        const unsigned long long below = m & ((1ull << lane) - 1ull);
        const int cp = __popcll(m);
        int basep = 0, basen = 0;
        if (lane == 0) {
            basep = atomicAdd(&npos, cp);
            basen = atomicAdd(&nneg, 64 - cp);
        }
        basep = __shfl(basep, 0);
        basen = __shfl(basen, 0);
        const int pbelow = (int)__popcll(below);
        if (isp) pos[basep + pbelow] = d;
        else     neg[basen + (lane - pbelow)] = d;
    }
    __syncthreads();
    const int np = npos, nn = nneg;

    float local = 0.f;
    for (int pi = 0; pi < np; ++pi) {
        const float dpm = pos[pi] + MARGIN;          // broadcast LDS read
        for (int n = tid; n < nn; n += 256)
            local += fmaxf(dpm - neg[n], 0.f);
    }

    #pragma unroll
    for (int off = 32; off > 0; off >>= 1) local += __shfl_down(local, off);
    if (lane == 0) wsum[tid >> 6] = local;
    __syncthreads();
    if (tid == 0) {
        long long V = 0;
        #pragma unroll
        for (int t = 0; t < NTYPES; ++t) {
            long long c = cnt[t];
            V += c * c * (long long)(BSZ - c);
        }
        double blocksum = (double)wsum[0] + (double)wsum[1]
                        + (double)wsum[2] + (double)wsum[3];
        float contrib = (float)(blocksum / (double)V);
        if (a == 0) {
            const long long B3 = (long long)BSZ * BSZ * BSZ;
            contrib += (float)((double)(B3 - V) * (double)MARGIN / (double)V);
        }
        atomicAdd(out, contrib);                     // plain relaxed atomic
    }
}

extern "C" void kernel_launch(void* const* d_in, const int* in_sizes, int n_in,
                              void* d_out, int out_size, void* d_ws, size_t ws_size,
                              hipStream_t stream) {
    const int* types = (const int*)d_in[0];
    const float* emb = (const float*)d_in[1];
    float* out = (float*)d_out;

    float* part = (float*)d_ws;                               // 4 MB
    float* ndiag = part + (size_t)KSPLIT * BSZ * BSZ;         // 8 KB

    dot_partial_kernel<<<256, 256, 0, stream>>>(emb, part, ndiag, out);
    triplet_kernel<<<BSZ, 256, 0, stream>>>(part, ndiag, types, out);
}

// Round 11
// 73.780 us; speedup vs baseline: 1.4064x; 1.0713x over previous
//
#include <hip/hip_runtime.h>
#include <hip/hip_bf16.h>

#define BSZ 512
#define DIM 768
#define KSPLIT 4
#define KSEG (DIM / KSPLIT)   // 192
#define TILE 64
#define NTYPES 16
#define MARGIN 1.0f
#define LDSPITCH (KSEG + 8)   // 200 ushorts = 400 B rows (16B-aligned, 2-way max)

typedef short bf16x8 __attribute__((ext_vector_type(8)));
typedef float f32x4 __attribute__((ext_vector_type(4)));

// ---------------------------------------------------------------------------
// Kernel 1: K-split partial dot GEMM via bf16 MFMA (16x16x32).
// grid = 256 = 4 ksplits x 64 tiles (1 block/CU).  64x64 tile per block:
// stage A(64) + B(64) rows x KSEG=192 as bf16 into row-major LDS (one
// barrier; fp32->bf16 via packed cvt in the staging path), then each of 4
// waves computes a 16x64 strip: per K-chunk of 32, 1 A-frag + 4 B-frag
// ds_read_b128 feed 4 MFMAs (~30 LDS reads/wave total vs 384 in the fp32
// VALU version, which was LDS-issue-bound at ~7.7us).
// Frag layouts (m89/m120-verified): A/B lane m=lane&15 reads 8 consecutive
// k at k0=8*(lane>>4); C/D col=lane&15, row=4*(lane>>4)+reg.
// Diagonal of the summed product = squared norms -> ndiag (so d(a,a)==0
// exactly).  Block 0 zeroes out[0] (cross-boundary visibility proven).
// NO grid sync / NO acquire-release (R5/R7/R9: cache-maintenance storms).
// Precision: bf16 quantization gives |delta d| ~ 2e-3 per distance, far
// below the 0.34 threshold.
// ---------------------------------------------------------------------------
__global__ __launch_bounds__(256) void dot_partial_kernel(
    const float* __restrict__ emb,
    float* __restrict__ part,       // [KSPLIT][BSZ][BSZ]
    float* __restrict__ ndiag,      // [KSPLIT][BSZ]
    float* __restrict__ out)
{
    const int tid = threadIdx.x;
    const int blk = blockIdx.x;
    const int ks = blk >> 6;          // 0..3
    const int tile = blk & 63;        // 0..63
    const int ti = tile >> 3, tj = tile & 7;
    const int i0 = ti * TILE, j0 = tj * TILE;

    if (blk == 0 && tid == 0) out[0] = 0.f;   // out is poisoned each launch

    __shared__ ushort sA[TILE][LDSPITCH];
    __shared__ ushort sB[TILE][LDSPITCH];

    // ---- stage 128 rows x 192 floats -> bf16 LDS (coalesced: 48 float4/row)
    #pragma unroll
    for (int it = 0; it < 24; ++it) {
        const int flat = it * 256 + tid;      // 0..6143
        const int row = flat / 48;            // 0..127
        const int c4 = flat - row * 48;       // 0..47
        const int grow = (row < TILE) ? (i0 + row) : (j0 + row - TILE);
        const float4 v = *(const float4*)(emb + (size_t)grow * DIM + ks * KSEG + c4 * 4);
        __hip_bfloat162 h0 = __float22bfloat162_rn(make_float2(v.x, v.y));
        __hip_bfloat162 h1 = __float22bfloat162_rn(make_float2(v.z, v.w));
        unsigned u0, u1;
        __builtin_memcpy(&u0, &h0, 4);
        __builtin_memcpy(&u1, &h1, 4);
        ushort* dst = (row < TILE) ? &sA[row][c4 * 4] : &sB[row - TILE][c4 * 4];
        *(uint2*)dst = make_uint2(u0, u1);
    }
    __syncthreads();

    // ---- MFMA: wave w -> rows [w*16, w*16+16), all 64 cols
    const int lane = tid & 63;
    const int w = tid >> 6;
    const int m = lane & 15;
    const int q = lane >> 4;          // 0..3

    f32x4 acc0 = {0.f, 0.f, 0.f, 0.f};
    f32x4 acc1 = {0.f, 0.f, 0.f, 0.f};
    f32x4 acc2 = {0.f, 0.f, 0.f, 0.f};
    f32x4 acc3 = {0.f, 0.f, 0.f, 0.f};

    const ushort* arow = &sA[w * 16 + m][q * 8];
    const ushort* b0r = &sB[0 * 16 + m][q * 8];
    const ushort* b1r = &sB[1 * 16 + m][q * 8];
    const ushort* b2r = &sB[2 * 16 + m][q * 8];
    const ushort* b3r = &sB[3 * 16 + m][q * 8];

    #pragma unroll
    for (int kc = 0; kc < KSEG / 32; ++kc) {       // 6 chunks
        const bf16x8 af = *(const bf16x8*)(arow + kc * 32);
        const bf16x8 bf0 = *(const bf16x8*)(b0r + kc * 32);
        const bf16x8 bf1 = *(const bf16x8*)(b1r + kc * 32);
        const bf16x8 bf2 = *(const bf16x8*)(b2r + kc * 32);
        const bf16x8 bf3 = *(const bf16x8*)(b3r + kc * 32);
        acc0 = __builtin_amdgcn_mfma_f32_16x16x32_bf16(af, bf0, acc0, 0, 0, 0);
        acc1 = __builtin_amdgcn_mfma_f32_16x16x32_bf16(af, bf1, acc1, 0, 0, 0);
        acc2 = __builtin_amdgcn_mfma_f32_16x16x32_bf16(af, bf2, acc2, 0, 0, 0);
        acc3 = __builtin_amdgcn_mfma_f32_16x16x32_bf16(af, bf3, acc3, 0, 0, 0);
    }

    // ---- epilogue: C/D layout col=m, row=4q+r
    float* pbuf = part + (size_t)ks * BSZ * BSZ;
    const int gi = i0 + w * 16 + 4 * q;
    #pragma unroll
    for (int r = 0; r < 4; ++r) {
        float* prow = pbuf + (size_t)(gi + r) * BSZ + j0;
        prow[0 * 16 + m] = acc0[r];
        prow[1 * 16 + m] = acc1[r];
        prow[2 * 16 + m] = acc2[r];
        prow[3 * 16 + m] = acc3[r];
    }
    // diagonal tiles: element (row==col) lives in tile nt==w at lanes m>>2==q
    if (ti == tj && (m >> 2) == q) {
        const f32x4 accw = (w == 0) ? acc0 : (w == 1) ? acc1 : (w == 2) ? acc2 : acc3;
        ndiag[ks * BSZ + i0 + w * 16 + m] = accw[m & 3];
    }
}

// ---------------------------------------------------------------------------
// Kernel 2: per-anchor triplet sum, self-contained finalize (unchanged from
// R10, 79.0us best).  nrm staged in LDS from 4 ndiag partials, distance on
// the fly from 4 partial streams, ballot compaction, |P|x|N| scan.  Each
// block computes V redundantly from a local LDS type-histogram and adds
// (blocksum/V) to out[0] with ONE plain device atomicAdd — no
// acquire/release, no ticket.  Block 0 adds the closed-form invalid-triplet
// term (B^3-V)*margin/V (reference adds margin to ALL entries pre-clamp).
// ---------------------------------------------------------------------------
__global__ __launch_bounds__(256) void triplet_kernel(
    const float* __restrict__ part, const float* __restrict__ ndiag,
    const int* __restrict__ types, float* __restrict__ out)
{
    const int a = blockIdx.x;
    const int tid = threadIdx.x;
    const int lane = tid & 63;
    __shared__ float nrm[BSZ];
    __shared__ float pos[BSZ], neg[BSZ];
    __shared__ int npos, nneg;
    __shared__ float wsum[4];
    __shared__ int cnt[NTYPES];
    if (tid == 0) { npos = 0; nneg = 0; }
    if (tid < NTYPES) cnt[tid] = 0;
    for (int j = tid; j < BSZ; j += 256)
        nrm[j] = ndiag[j] + ndiag[BSZ + j] + ndiag[2 * BSZ + j] + ndiag[3 * BSZ + j];
    const int ta = types[a];
    __syncthreads();

    const float na = nrm[a];
    const size_t rb = (size_t)a * BSZ;
    const size_t PS = (size_t)BSZ * BSZ;

    for (int j = tid; j < BSZ; j += 256) {
        const int tj = types[j];
        atomicAdd(&cnt[tj], 1);                      // local histogram for V
        const float sp = part[rb + j] + part[PS + rb + j]
                       + part[2 * PS + rb + j] + part[3 * PS + rb + j];
        const float d = sqrtf(fmaxf(na + nrm[j] - 2.f * sp, 0.f));
        const bool isp = (tj == ta);
        const unsigned long long mm = __ballot(isp);
        const unsigned long long below = mm & ((1ull << lane) - 1ull);
        const int cp = __popcll(mm);
        int basep = 0, basen = 0;
        if (lane == 0) {
            basep = atomicAdd(&npos, cp);
            basen = atomicAdd(&nneg, 64 - cp);
        }
        basep = __shfl(basep, 0);
        basen = __shfl(basen, 0);
        const int pbelow = (int)__popcll(below);
        if (isp) pos[basep + pbelow] = d;
        else     neg[basen + (lane - pbelow)] = d;
    }
    __syncthreads();
    const int np = npos, nn = nneg;

    float local = 0.f;
    for (int pi = 0; pi < np; ++pi) {
        const float dpm = pos[pi] + MARGIN;          // broadcast LDS read
        for (int n = tid; n < nn; n += 256)
            local += fmaxf(dpm - neg[n], 0.f);
    }

    #pragma unroll
    for (int off = 32; off > 0; off >>= 1) local += __shfl_down(local, off);
    if (lane == 0) wsum[tid >> 6] = local;
    __syncthreads();
    if (tid == 0) {
        long long V = 0;
        #pragma unroll
        for (int t = 0; t < NTYPES; ++t) {
            long long c = cnt[t];
            V += c * c * (long long)(BSZ - c);
        }
        double blocksum = (double)wsum[0] + (double)wsum[1]
                        + (double)wsum[2] + (double)wsum[3];
        float contrib = (float)(blocksum / (double)V);
        if (a == 0) {
            const long long B3 = (long long)BSZ * BSZ * BSZ;
            contrib += (float)((double)(B3 - V) * (double)MARGIN / (double)V);
        }
        atomicAdd(out, contrib);                     // plain relaxed atomic
    }
}

extern "C" void kernel_launch(void* const* d_in, const int* in_sizes, int n_in,
                              void* d_out, int out_size, void* d_ws, size_t ws_size,
                              hipStream_t stream) {
    const int* types = (const int*)d_in[0];
    const float* emb = (const float*)d_in[1];
    float* out = (float*)d_out;

    float* part = (float*)d_ws;                               // 4 MB
    float* ndiag = part + (size_t)KSPLIT * BSZ * BSZ;         // 8 KB

    dot_partial_kernel<<<256, 256, 0, stream>>>(emb, part, ndiag, out);
    triplet_kernel<<<BSZ, 256, 0, stream>>>(part, ndiag, types, out);
}